// Round 3
// baseline (7482.202 us; speedup 1.0000x reference)
//
#include <hip/hip_runtime.h>
#include <hip/hip_bf16.h>
#include <stdint.h>

#define C_IN  128
#define O_CH  256
#define NH    5
#define TSIZE 2048
#define HWDIM 56
#define NPIX  3136        // 56*56
#define KTOT  1152        // 128*9
#define ADIM  1161        // KTOT + 9

// ---------------- table build (fp64 decision path) ----------------
__global__ void k_norms(const float* __restrict__ w, double* __restrict__ ssbuf) {
  int o = blockIdx.x, t = threadIdx.x;            // 64 threads
  double ss = 0.;
  for (int i = t; i < KTOT; i += 64) { double v = (double)w[o * KTOT + i]; ss += v * v; }
  #pragma unroll
  for (int off = 32; off > 0; off >>= 1) ss += __shfl_down(ss, off, 64);
  if (t == 0) ssbuf[o] = ss;
}

__global__ __launch_bounds__(256) void k_table(const float* __restrict__ w,
    const float* __restrict__ a, const float* __restrict__ b_unit,
    const double* __restrict__ ssbuf, int* __restrict__ kbucket) {
  int o = blockIdx.x, t = threadIdx.x;
  __shared__ double red[256];
  __shared__ double r6[6][256];
  red[t] = ssbuf[t];
  __syncthreads();
  for (int s = 128; s; s >>= 1) { if (t < s) red[t] = fmax(red[t], red[t + s]); __syncthreads(); }
  double scale = 0.99 / sqrt(red[0]);             // U / denom
  double pd0 = 0, pd1 = 0, pd2 = 0, pd3 = 0, pd4 = 0, ss2 = 0;
  for (int i = t; i < KTOT; i += 256) {
    double wv = scale * (double)w[o * KTOT + i];
    ss2 += wv * wv;
    pd0 += wv * (double)a[0 * ADIM + i];
    pd1 += wv * (double)a[1 * ADIM + i];
    pd2 += wv * (double)a[2 * ADIM + i];
    pd3 += wv * (double)a[3 * ADIM + i];
    pd4 += wv * (double)a[4 * ADIM + i];
  }
  r6[0][t] = ss2; r6[1][t] = pd0; r6[2][t] = pd1; r6[3][t] = pd2; r6[4][t] = pd3; r6[5][t] = pd4;
  __syncthreads();
  for (int s = 128; s; s >>= 1) {
    if (t < s) { for (int q = 0; q < 6; ++q) r6[q][t] += r6[q][t + s]; }
    __syncthreads();
  }
  if (t == 0) {
    double nrm = sqrt(r6[0][0]);
    double q = nrm;
    double dp[NH] = {0, 0, 0, 0, 0};
    for (int j = 0; j < 9; ++j) {
      q = q * q;                                   // nrm^2, nrm^4, ..., nrm^512
      #pragma unroll
      for (int h = 0; h < NH; ++h) dp[h] += q * (double)a[h * ADIM + KTOT + j];
    }
    #pragma unroll
    for (int h = 0; h < NH; ++h) {
      double tot = r6[1 + h][0] + dp[h] + (double)b_unit[h] * 4.0;
      int hv = (int)floor(tot * 0.25);
      int bk = hv % TSIZE; if (bk < 0) bk = -bk;
      kbucket[o * NH + h] = bk;
    }
  }
}

// ---------------- vote conv (fp64, boundary-exact) ----------------
__global__ __launch_bounds__(256) void k_vote(const float* __restrict__ x,
    const float* __restrict__ a, const float* __restrict__ b_unit, int* __restrict__ hist) {
  __shared__ int lh[NH * TSIZE];
  int t = threadIdx.x;
  for (int i = t; i < NH * TSIZE; i += 256) lh[i] = 0;
  __syncthreads();
  int p = blockIdx.x * 256 + t;                   // exactly 100352
  int b = p / NPIX; int rem = p - b * NPIX;
  int y = rem / HWDIM; int xx = rem - y * HWDIM;
  double acc[NH] = {0, 0, 0, 0, 0};
  const float* xb = x + (size_t)(b * C_IN) * NPIX + y * HWDIM + xx;
  bool x0 = xx > 0, x2 = xx < HWDIM - 1, y0 = y > 0, y2 = y < HWDIM - 1;
  for (int c = 0; c < C_IN; ++c) {
    const float* xc = xb + c * NPIX;
    double v0 = 0, v1 = 0, v2 = 0, v3 = 0, v5 = 0, v6 = 0, v7 = 0, v8 = 0;
    double v4 = (double)xc[0];
    if (x0) v3 = (double)xc[-1];
    if (x2) v5 = (double)xc[1];
    if (y0) { v1 = (double)xc[-HWDIM]; if (x0) v0 = (double)xc[-HWDIM - 1]; if (x2) v2 = (double)xc[-HWDIM + 1]; }
    if (y2) { v7 = (double)xc[HWDIM];  if (x0) v6 = (double)xc[HWDIM - 1];  if (x2) v8 = (double)xc[HWDIM + 1]; }
    #pragma unroll
    for (int h = 0; h < NH; ++h) {
      const float* ah = a + h * ADIM + c * 9;     // uniform -> scalar loads
      acc[h] += v0 * (double)ah[0] + v1 * (double)ah[1] + v2 * (double)ah[2]
              + v3 * (double)ah[3] + v4 * (double)ah[4] + v5 * (double)ah[5]
              + v6 * (double)ah[6] + v7 * (double)ah[7] + v8 * (double)ah[8];
    }
  }
  #pragma unroll
  for (int h = 0; h < NH; ++h) {
    const float* ah = a + h * ADIM + KTOT;        // appended 0.5 channel (zero in pad ring)
    double s = (double)ah[4];
    if (x0) s += (double)ah[3];
    if (x2) s += (double)ah[5];
    if (y0) { s += (double)ah[1]; if (x0) s += (double)ah[0]; if (x2) s += (double)ah[2]; }
    if (y2) { s += (double)ah[7]; if (x0) s += (double)ah[6]; if (x2) s += (double)ah[8]; }
    acc[h] += 0.5 * s;
    int hv = (int)floor((acc[h] + (double)b_unit[h] * 4.0) * 0.25);
    int bk = hv % TSIZE; if (bk < 0) bk = -bk;
    atomicAdd(&lh[h * TSIZE + bk], 1);
  }
  __syncthreads();
  for (int i = t; i < NH * TSIZE; i += 256) { int v = lh[i]; if (v) atomicAdd(&hist[i], v); }
}

// ---------------- select + active mask ----------------
__global__ __launch_bounds__(256) void k_select(const int* __restrict__ hist,
    const int* __restrict__ kbucket, float* __restrict__ mscale) {
  int t = threadIdx.x;
  __shared__ int rc[256], ri[256], sel[NH], cnt[256];
  for (int h = 0; h < NH; ++h) {
    int bc = -1, bi = 0;
    for (int i = t; i < TSIZE; i += 256) {        // ascending i + strict '>' = first-max
      int c = hist[h * TSIZE + i];
      if (c > bc) { bc = c; bi = i; }
    }
    rc[t] = bc; ri[t] = bi;
    __syncthreads();
    for (int s = 128; s; s >>= 1) {
      if (t < s) {
        if (rc[t + s] > rc[t] || (rc[t + s] == rc[t] && ri[t + s] < ri[t])) {
          rc[t] = rc[t + s]; ri[t] = ri[t + s];
        }
      }
      __syncthreads();
    }
    if (t == 0) sel[h] = ri[0];
    __syncthreads();
  }
  bool act = false;
  #pragma unroll
  for (int i = 0; i < NH; ++i) {
    int kb = kbucket[t * NH + i];
    #pragma unroll
    for (int j = 0; j < NH; ++j) act = act || (kb == sel[j]);
  }
  cnt[t] = act ? 1 : 0;
  __syncthreads();
  for (int s = 128; s; s >>= 1) { if (t < s) cnt[t] += cnt[t + s]; __syncthreads(); }
  int n = cnt[0];
  bool a2 = act;
  if (n == 0) { a2 = true; n = 256; }             // fallback: all active
  mscale[t] = a2 ? 256.0f / (float)n : 0.0f;
}

// ---------------- DIAGNOSTIC value path: fp32 direct conv ----------------
// Independent indexing, no packing, no big workspace. Isolates decision path
// correctness from the MFMA/staging value path.
__global__ __launch_bounds__(256) void k_dconv(const float* __restrict__ x,
    const float* __restrict__ w, const float* __restrict__ bias,
    const float* __restrict__ mscale, float* __restrict__ out) {
  int bid = blockIdx.x;                           // (b, o, yq): ((b*256 + o)*14 + yq)
  int yq = bid % 14; int rem = bid / 14;
  int o = rem & 255; int b = rem >> 8;
  __shared__ float wsm[KTOT];
  for (int i = threadIdx.x; i < KTOT; i += 256) wsm[i] = w[o * KTOT + i];
  __syncthreads();
  int t = threadIdx.x;
  if (t >= 224) return;                           // 4 rows * 56 cols
  int y = yq * 4 + t / HWDIM;
  int xx = t % HWDIM;
  const float* xb = x + (size_t)b * C_IN * NPIX + y * HWDIM + xx;
  float acc = 0.f;
  bool y0 = y > 0, y2 = y < HWDIM - 1, x0 = xx > 0, x2 = xx < HWDIM - 1;
  for (int c = 0; c < C_IN; ++c) {
    const float* xc = xb + c * NPIX;
    const float* wc9 = wsm + c * 9;               // [ky*3+kx]
    float s = xc[0] * wc9[4];
    if (x0) s += xc[-1] * wc9[3];
    if (x2) s += xc[1] * wc9[5];
    if (y0) { s += xc[-HWDIM] * wc9[1]; if (x0) s += xc[-HWDIM - 1] * wc9[0]; if (x2) s += xc[-HWDIM + 1] * wc9[2]; }
    if (y2) { s += xc[HWDIM] * wc9[7];  if (x0) s += xc[HWDIM - 1] * wc9[6];  if (x2) s += xc[HWDIM + 1] * wc9[8]; }
    acc += s;
  }
  out[((size_t)b * O_CH + o) * NPIX + y * HWDIM + xx] = (acc + bias[o]) * mscale[o];
}

extern "C" void kernel_launch(void* const* d_in, const int* in_sizes, int n_in,
                              void* d_out, int out_size, void* d_ws, size_t ws_size,
                              hipStream_t stream) {
  const float* x      = (const float*)d_in[0];
  const float* w      = (const float*)d_in[1];
  const float* bias   = (const float*)d_in[2];
  const float* a      = (const float*)d_in[3];
  const float* b_unit = (const float*)d_in[4];
  float* out = (float*)d_out;
  char* ws = (char*)d_ws;
  // tiny workspace layout (bytes) — total 49,152
  int*    hist    = (int*)   (ws);                              // 5*2048*4 = 40,960
  double* ssbuf   = (double*)(ws + 40960);                      // 256*8    ->  43,008
  int*    kbucket = (int*)   (ws + 43008);                      // 256*5*4  ->  48,128
  float*  mscale  = (float*) (ws + 48128);                      // 256*4    ->  49,152

  hipMemsetAsync(hist, 0, 40960, stream);
  k_norms <<<256, 64, 0, stream>>>(w, ssbuf);
  k_table <<<256, 256, 0, stream>>>(w, a, b_unit, ssbuf, kbucket);
  k_vote  <<<392, 256, 0, stream>>>(x, a, b_unit, hist);
  k_select<<<1, 256, 0, stream>>>(hist, kbucket, mscale);
  k_dconv <<<32 * 256 * 14, 256, 0, stream>>>(x, w, bias, mscale, out);
}

// Round 4
// 488.398 us; speedup vs baseline: 15.3199x; 15.3199x over previous
//
#include <hip/hip_runtime.h>
#include <hip/hip_bf16.h>
#include <stdint.h>

typedef __attribute__((ext_vector_type(8))) short  short8;   // 8 x bf16 fragment
typedef __attribute__((ext_vector_type(4))) float  f32x4;
typedef __attribute__((ext_vector_type(4))) unsigned int u32x4;

#define C_IN  128
#define O_CH  256
#define NH    5
#define TSIZE 2048
#define HWDIM 56
#define NPIX  3136        // 56*56
#define KTOT  1152        // 128*9
#define ADIM  1161        // KTOT + 9
#define PADW  58
#define PPIX  3364        // 58*58

static __device__ __forceinline__ unsigned short f2bf(float f) {
  unsigned int u = __float_as_uint(f);
  return (unsigned short)((u + 0x7fffu + ((u >> 16) & 1u)) >> 16);   // RNE
}
static __device__ __forceinline__ float bf2f(unsigned short h) {
  return __uint_as_float((unsigned int)h << 16);
}

// ---------------- table build (fp64 decision path — verified R3) ----------------
__global__ void k_norms(const float* __restrict__ w, double* __restrict__ ssbuf) {
  int o = blockIdx.x, t = threadIdx.x;            // 64 threads
  double ss = 0.;
  for (int i = t; i < KTOT; i += 64) { double v = (double)w[o * KTOT + i]; ss += v * v; }
  #pragma unroll
  for (int off = 32; off > 0; off >>= 1) ss += __shfl_down(ss, off, 64);
  if (t == 0) ssbuf[o] = ss;
}

__global__ __launch_bounds__(256) void k_table(const float* __restrict__ w,
    const float* __restrict__ a, const float* __restrict__ b_unit,
    const double* __restrict__ ssbuf, int* __restrict__ kbucket) {
  int o = blockIdx.x, t = threadIdx.x;
  __shared__ double red[256];
  __shared__ double r6[6][256];
  red[t] = ssbuf[t];
  __syncthreads();
  for (int s = 128; s; s >>= 1) { if (t < s) red[t] = fmax(red[t], red[t + s]); __syncthreads(); }
  double scale = 0.99 / sqrt(red[0]);             // U / denom
  double pd0 = 0, pd1 = 0, pd2 = 0, pd3 = 0, pd4 = 0, ss2 = 0;
  for (int i = t; i < KTOT; i += 256) {
    double wv = scale * (double)w[o * KTOT + i];
    ss2 += wv * wv;
    pd0 += wv * (double)a[0 * ADIM + i];
    pd1 += wv * (double)a[1 * ADIM + i];
    pd2 += wv * (double)a[2 * ADIM + i];
    pd3 += wv * (double)a[3 * ADIM + i];
    pd4 += wv * (double)a[4 * ADIM + i];
  }
  r6[0][t] = ss2; r6[1][t] = pd0; r6[2][t] = pd1; r6[3][t] = pd2; r6[4][t] = pd3; r6[5][t] = pd4;
  __syncthreads();
  for (int s = 128; s; s >>= 1) {
    if (t < s) { for (int q = 0; q < 6; ++q) r6[q][t] += r6[q][t + s]; }
    __syncthreads();
  }
  if (t == 0) {
    double nrm = sqrt(r6[0][0]);
    double q = nrm;
    double dp[NH] = {0, 0, 0, 0, 0};
    for (int j = 0; j < 9; ++j) {
      q = q * q;                                   // nrm^2, nrm^4, ..., nrm^512
      #pragma unroll
      for (int h = 0; h < NH; ++h) dp[h] += q * (double)a[h * ADIM + KTOT + j];
    }
    #pragma unroll
    for (int h = 0; h < NH; ++h) {
      double tot = r6[1 + h][0] + dp[h] + (double)b_unit[h] * 4.0;
      int hv = (int)floor(tot * 0.25);
      int bk = hv % TSIZE; if (bk < 0) bk = -bk;
      kbucket[o * NH + h] = bk;
    }
  }
}

// ---------------- vote conv (fp64, boundary-exact — verified R3) ----------------
__global__ __launch_bounds__(256) void k_vote(const float* __restrict__ x,
    const float* __restrict__ a, const float* __restrict__ b_unit, int* __restrict__ hist) {
  __shared__ int lh[NH * TSIZE];
  int t = threadIdx.x;
  for (int i = t; i < NH * TSIZE; i += 256) lh[i] = 0;
  __syncthreads();
  int p = blockIdx.x * 256 + t;                   // exactly 100352
  int b = p / NPIX; int rem = p - b * NPIX;
  int y = rem / HWDIM; int xx = rem - y * HWDIM;
  double acc[NH] = {0, 0, 0, 0, 0};
  const float* xb = x + (size_t)(b * C_IN) * NPIX + y * HWDIM + xx;
  bool x0 = xx > 0, x2 = xx < HWDIM - 1, y0 = y > 0, y2 = y < HWDIM - 1;
  for (int c = 0; c < C_IN; ++c) {
    const float* xc = xb + c * NPIX;
    double v0 = 0, v1 = 0, v2 = 0, v3 = 0, v5 = 0, v6 = 0, v7 = 0, v8 = 0;
    double v4 = (double)xc[0];
    if (x0) v3 = (double)xc[-1];
    if (x2) v5 = (double)xc[1];
    if (y0) { v1 = (double)xc[-HWDIM]; if (x0) v0 = (double)xc[-HWDIM - 1]; if (x2) v2 = (double)xc[-HWDIM + 1]; }
    if (y2) { v7 = (double)xc[HWDIM];  if (x0) v6 = (double)xc[HWDIM - 1];  if (x2) v8 = (double)xc[HWDIM + 1]; }
    #pragma unroll
    for (int h = 0; h < NH; ++h) {
      const float* ah = a + h * ADIM + c * 9;     // uniform -> scalar loads
      acc[h] += v0 * (double)ah[0] + v1 * (double)ah[1] + v2 * (double)ah[2]
              + v3 * (double)ah[3] + v4 * (double)ah[4] + v5 * (double)ah[5]
              + v6 * (double)ah[6] + v7 * (double)ah[7] + v8 * (double)ah[8];
    }
  }
  #pragma unroll
  for (int h = 0; h < NH; ++h) {
    const float* ah = a + h * ADIM + KTOT;        // appended 0.5 channel (zero in pad ring)
    double s = (double)ah[4];
    if (x0) s += (double)ah[3];
    if (x2) s += (double)ah[5];
    if (y0) { s += (double)ah[1]; if (x0) s += (double)ah[0]; if (x2) s += (double)ah[2]; }
    if (y2) { s += (double)ah[7]; if (x0) s += (double)ah[6]; if (x2) s += (double)ah[8]; }
    acc[h] += 0.5 * s;
    int hv = (int)floor((acc[h] + (double)b_unit[h] * 4.0) * 0.25);
    int bk = hv % TSIZE; if (bk < 0) bk = -bk;
    atomicAdd(&lh[h * TSIZE + bk], 1);
  }
  __syncthreads();
  for (int i = t; i < NH * TSIZE; i += 256) { int v = lh[i]; if (v) atomicAdd(&hist[i], v); }
}

// ---------------- select + active mask (verified R3) ----------------
__global__ __launch_bounds__(256) void k_select(const int* __restrict__ hist,
    const int* __restrict__ kbucket, float* __restrict__ mscale) {
  int t = threadIdx.x;
  __shared__ int rc[256], ri[256], sel[NH], cnt[256];
  for (int h = 0; h < NH; ++h) {
    int bc = -1, bi = 0;
    for (int i = t; i < TSIZE; i += 256) {        // ascending i + strict '>' = first-max
      int c = hist[h * TSIZE + i];
      if (c > bc) { bc = c; bi = i; }
    }
    rc[t] = bc; ri[t] = bi;
    __syncthreads();
    for (int s = 128; s; s >>= 1) {
      if (t < s) {
        if (rc[t + s] > rc[t] || (rc[t + s] == rc[t] && ri[t + s] < ri[t])) {
          rc[t] = rc[t + s]; ri[t] = ri[t + s];
        }
      }
      __syncthreads();
    }
    if (t == 0) sel[h] = ri[0];
    __syncthreads();
  }
  bool act = false;
  #pragma unroll
  for (int i = 0; i < NH; ++i) {
    int kb = kbucket[t * NH + i];
    #pragma unroll
    for (int j = 0; j < NH; ++j) act = act || (kb == sel[j]);
  }
  cnt[t] = act ? 1 : 0;
  __syncthreads();
  for (int s = 128; s; s >>= 1) { if (t < s) cnt[t] += cnt[t + s]; __syncthreads(); }
  int n = cnt[0];
  bool a2 = act;
  if (n == 0) { a2 = true; n = 256; }             // fallback: all active
  mscale[t] = a2 ? 256.0f / (float)n : 0.0f;
}

// ---------------- packing: hi/lo split bf16 ----------------
__global__ void k_packw2(const float* __restrict__ w,
                         unsigned short* __restrict__ wph, unsigned short* __restrict__ wpl) {
  int idx = blockIdx.x * 256 + threadIdx.x;       // < 294912 exact
  int o = idx / KTOT; int r = idx - o * KTOT;
  int kyx = r >> 7; int c = r & 127;
  float v = w[o * KTOT + c * 9 + kyx];
  unsigned short h = f2bf(v);
  wph[idx] = h;
  wpl[idx] = f2bf(v - bf2f(h));
}

__global__ __launch_bounds__(256) void k_packx2(const float* __restrict__ x, int b0,
    unsigned short* __restrict__ xph, unsigned short* __restrict__ xpl) {
  int bl = blockIdx.x / HWDIM; int y = blockIdx.x - bl * HWDIM;   // bl = slice-local batch
  int t = threadIdx.x;
  __shared__ unsigned short th[C_IN * 57];        // +1 pad on 56
  __shared__ unsigned short tl[C_IN * 57];
  const float* xb = x + (size_t)((b0 + bl) * C_IN) * NPIX + y * HWDIM;
  for (int i = t; i < C_IN * HWDIM; i += 256) {
    int c = i / HWDIM; int xx = i - c * HWDIM;
    float v = xb[c * NPIX + xx];
    unsigned short h = f2bf(v);
    th[c * 57 + xx] = h;
    tl[c * 57 + xx] = f2bf(v - bf2f(h));
  }
  __syncthreads();
  size_t base = ((size_t)(bl * PADW + y + 1) * PADW + 1) * C_IN;  // = bl*PPIX + (y+1)*PADW + 1, *C_IN
  for (int i = t; i < C_IN * HWDIM; i += 256) {
    int xx = i >> 7; int c = i & 127;
    xph[base + xx * C_IN + c] = th[c * 57 + xx];
    xpl[base + xx * C_IN + c] = tl[c * 57 + xx];
  }
}

// ---------------- main conv: split-bf16 implicit GEMM (hh+hl+lh MFMA) ----------------
__global__ __launch_bounds__(256) void k_gemm2(
    const unsigned short* __restrict__ xph, const unsigned short* __restrict__ xpl,
    const unsigned short* __restrict__ wph, const unsigned short* __restrict__ wpl,
    const float* __restrict__ bias, const float* __restrict__ mscale,
    float* __restrict__ out, int b0) {
  int mtile = blockIdx.x >> 1;                    // M-tiles of 128 pixels (slice-local)
  int ntile = blockIdx.x & 1;                     // 2 N-tiles of 128 out-channels
  int tid = threadIdx.x;
  int lane = tid & 63, wv = tid >> 6;
  int wr = wv >> 1, wc = wv & 1;                  // 2x2 wave grid, 64x64 each
  __shared__ __attribute__((aligned(16))) unsigned short Ah[128 * 64];
  __shared__ __attribute__((aligned(16))) unsigned short Al[128 * 64];
  __shared__ __attribute__((aligned(16))) unsigned short Bh[128 * 64];
  __shared__ __attribute__((aligned(16))) unsigned short Bl[128 * 64];
  int baseA[4], baseB[4];
  #pragma unroll
  for (int j = 0; j < 4; ++j) {
    int g = j * 256 + tid;                        // 0..1023 : (m, k8) slots
    int mloc = g >> 3, k8 = (g & 7) * 8;
    int mg = mtile * 128 + mloc;
    int bb = (unsigned)mg / NPIX; int rem = mg - bb * NPIX;
    int y = (unsigned)rem / HWDIM; int xx = rem - y * HWDIM;
    baseA[j] = ((bb * PPIX + y * PADW + xx) << 7) + k8;     // padded-x element offset
    baseB[j] = (ntile * 128 + mloc) * KTOT + k8;            // w^T element offset
  }
  f32x4 acc[4][4];
  #pragma unroll
  for (int mi = 0; mi < 4; ++mi)
    #pragma unroll
    for (int ni = 0; ni < 4; ++ni) acc[mi][ni] = (f32x4){0.f, 0.f, 0.f, 0.f};

  for (int t = 0; t < 18; ++t) {                  // K = 1152 = 9 taps * 2 c-halves of 64
    int kyx = t >> 1;
    int ky = kyx / 3, kx = kyx - ky * 3;
    int koff = ((ky * PADW + kx) << 7) + ((t & 1) << 6);
    u32x4 vah[4], val_[4], vbh[4], vbl[4];
    #pragma unroll
    for (int j = 0; j < 4; ++j) {
      vah[j]  = *(const u32x4*)(xph + baseA[j] + koff);
      val_[j] = *(const u32x4*)(xpl + baseA[j] + koff);
      vbh[j]  = *(const u32x4*)(wph + baseB[j] + t * 64);
      vbl[j]  = *(const u32x4*)(wpl + baseB[j] + t * 64);
    }
    __syncthreads();
    #pragma unroll
    for (int j = 0; j < 4; ++j) {
      *(u32x4*)&Ah[(j * 256 + tid) * 8] = vah[j];
      *(u32x4*)&Al[(j * 256 + tid) * 8] = val_[j];
      *(u32x4*)&Bh[(j * 256 + tid) * 8] = vbh[j];
      *(u32x4*)&Bl[(j * 256 + tid) * 8] = vbl[j];
    }
    __syncthreads();
    #pragma unroll
    for (int kk = 0; kk < 64; kk += 32) {
      int kc = kk + ((lane >> 4) << 3);
      int ar = lane & 15;
      short8 fah[4], fal[4], fbh[4], fbl[4];
      #pragma unroll
      for (int mi = 0; mi < 4; ++mi) {
        fah[mi] = *(const short8*)&Ah[(wr * 64 + mi * 16 + ar) * 64 + kc];
        fal[mi] = *(const short8*)&Al[(wr * 64 + mi * 16 + ar) * 64 + kc];
      }
      #pragma unroll
      for (int ni = 0; ni < 4; ++ni) {
        fbh[ni] = *(const short8*)&Bh[(wc * 64 + ni * 16 + ar) * 64 + kc];
        fbl[ni] = *(const short8*)&Bl[(wc * 64 + ni * 16 + ar) * 64 + kc];
      }
      #pragma unroll
      for (int mi = 0; mi < 4; ++mi)
        #pragma unroll
        for (int ni = 0; ni < 4; ++ni) {
          acc[mi][ni] = __builtin_amdgcn_mfma_f32_16x16x32_bf16(fal[mi], fbh[ni], acc[mi][ni], 0, 0, 0);
          acc[mi][ni] = __builtin_amdgcn_mfma_f32_16x16x32_bf16(fah[mi], fbl[ni], acc[mi][ni], 0, 0, 0);
          acc[mi][ni] = __builtin_amdgcn_mfma_f32_16x16x32_bf16(fah[mi], fbh[ni], acc[mi][ni], 0, 0, 0);
        }
    }
  }
  // epilogue: D col = lane&15 (o), row = (lane>>4)*4+j (m)  [m89-verified layout]
  int r4 = (lane >> 4) << 2;
  int cn = lane & 15;
  #pragma unroll
  for (int ni = 0; ni < 4; ++ni) {
    int o = ntile * 128 + wc * 64 + ni * 16 + cn;
    float ms = mscale[o], bi = bias[o];
    #pragma unroll
    for (int mi = 0; mi < 4; ++mi) {
      int mg = mtile * 128 + wr * 64 + mi * 16 + r4;
      int bb = (unsigned)mg / NPIX; int pix = mg - bb * NPIX;   // mg%4==0, NPIX%4==0: vec never crosses batch
      f32x4 v;
      #pragma unroll
      for (int j = 0; j < 4; ++j) v[j] = (acc[mi][ni][j] + bi) * ms;
      *(f32x4*)(out + (size_t)(((b0 + bb) << 8) + o) * NPIX + pix) = v;
    }
  }
}

// ---------------- fallback value path (R3-verified): fp32 direct conv ----------------
__global__ __launch_bounds__(256) void k_dconv(const float* __restrict__ x,
    const float* __restrict__ w, const float* __restrict__ bias,
    const float* __restrict__ mscale, float* __restrict__ out) {
  int bid = blockIdx.x;
  int yq = bid % 14; int rem = bid / 14;
  int o = rem & 255; int b = rem >> 8;
  __shared__ float wsm[KTOT];
  for (int i = threadIdx.x; i < KTOT; i += 256) wsm[i] = w[o * KTOT + i];
  __syncthreads();
  int t = threadIdx.x;
  if (t >= 224) return;
  int y = yq * 4 + t / HWDIM;
  int xx = t % HWDIM;
  const float* xb = x + (size_t)b * C_IN * NPIX + y * HWDIM + xx;
  float acc = 0.f;
  bool y0 = y > 0, y2 = y < HWDIM - 1, x0 = xx > 0, x2 = xx < HWDIM - 1;
  for (int c = 0; c < C_IN; ++c) {
    const float* xc = xb + c * NPIX;
    const float* wc9 = wsm + c * 9;
    float s = xc[0] * wc9[4];
    if (x0) s += xc[-1] * wc9[3];
    if (x2) s += xc[1] * wc9[5];
    if (y0) { s += xc[-HWDIM] * wc9[1]; if (x0) s += xc[-HWDIM - 1] * wc9[0]; if (x2) s += xc[-HWDIM + 1] * wc9[2]; }
    if (y2) { s += xc[HWDIM] * wc9[7];  if (x0) s += xc[HWDIM - 1] * wc9[6];  if (x2) s += xc[HWDIM + 1] * wc9[8]; }
    acc += s;
  }
  out[((size_t)b * O_CH + o) * NPIX + y * HWDIM + xx] = (acc + bias[o]) * mscale[o];
}

extern "C" void kernel_launch(void* const* d_in, const int* in_sizes, int n_in,
                              void* d_out, int out_size, void* d_ws, size_t ws_size,
                              hipStream_t stream) {
  const float* x      = (const float*)d_in[0];
  const float* w      = (const float*)d_in[1];
  const float* bias   = (const float*)d_in[2];
  const float* a      = (const float*)d_in[3];
  const float* b_unit = (const float*)d_in[4];
  float* out = (float*)d_out;
  char* ws = (char*)d_ws;

  // fixed small region: 49,152 bytes
  int*    hist    = (int*)   (ws);                              // 40,960
  double* ssbuf   = (double*)(ws + 40960);                      //  2,048
  int*    kbucket = (int*)   (ws + 43008);                      //  5,120
  float*  mscale  = (float*) (ws + 48128);                      //  1,024 -> 49,152

  hipMemsetAsync(hist, 0, 40960, stream);
  k_norms <<<256, 64, 0, stream>>>(w, ssbuf);
  k_table <<<256, 256, 0, stream>>>(w, a, b_unit, ssbuf, kbucket);
  k_vote  <<<392, 256, 0, stream>>>(x, a, b_unit, hist);
  k_select<<<1, 256, 0, stream>>>(hist, kbucket, mscale);

  // ws-adaptive batch slicing for the split-bf16 GEMM path
  const size_t SMALL = 49152;
  const size_t WPT   = 589824;                    // 256*1152*2 per buffer
  const size_t XPB   = 861184;                    // 3364*128*2 per batch per buffer
  int NB = 0;
  for (int nb = 32; nb >= 2; nb -= 2)
    if (SMALL + 2 * WPT + 2 * (size_t)nb * XPB <= ws_size) { NB = nb; break; }

  if (NB == 0) {                                  // ws too small: verified fallback
    k_dconv<<<32 * 256 * 14, 256, 0, stream>>>(x, w, bias, mscale, out);
    return;
  }

  unsigned short* wph = (unsigned short*)(ws + SMALL);
  unsigned short* wpl = (unsigned short*)(ws + SMALL + WPT);
  unsigned short* xph = (unsigned short*)(ws + SMALL + 2 * WPT);
  unsigned short* xpl = (unsigned short*)(ws + SMALL + 2 * WPT + (size_t)NB * XPB);

  k_packw2<<<1152, 256, 0, stream>>>(w, wph, wpl);
  hipMemsetAsync(xph, 0, (size_t)NB * XPB, stream);   // zero pad ring once; interiors rewritten per slice
  hipMemsetAsync(xpl, 0, (size_t)NB * XPB, stream);

  for (int b0 = 0; b0 < 32; b0 += NB) {
    int nb = NB < (32 - b0) ? NB : (32 - b0);     // even (NB even, 32 even)
    k_packx2<<<nb * HWDIM, 256, 0, stream>>>(x, b0, xph, xpl);
    int mtiles = nb * NPIX / 128;                 // nb even -> exact
    k_gemm2<<<mtiles * 2, 256, 0, stream>>>(xph, xpl, wph, wpl, bias, mscale, out, b0);
  }
}